// Round 18
// baseline (3131.007 us; speedup 1.0000x reference)
//
#include <hip/hip_runtime.h>
#include <hip/hip_bf16.h>
#include <math.h>

#define N_NODES   100000
#define IN_DIM    256
#define HIDDEN    512
#define N_INC     1000000
#define N_SEG     100000
#define NCHUNK    782          // ceil(N_SEG / 128)
#define GRP       33           // 32 producer blocks + 1 consumer block per chunk

typedef __attribute__((ext_vector_type(8))) short bf16x8;
typedef __attribute__((ext_vector_type(4))) float f32x4;

__device__ __forceinline__ unsigned short f2bf(float f) {
  unsigned int u = __builtin_bit_cast(unsigned int, f);
  u += 0x7FFFu + ((u >> 16) & 1u);   // RNE
  return (unsigned short)(u >> 16);
}
__device__ __forceinline__ float bflo(unsigned int u) {   // low bf16 -> f32
  return __builtin_bit_cast(float, u << 16);
}
__device__ __forceinline__ float bfhi(unsigned int u) {   // high bf16 -> f32
  return __builtin_bit_cast(float, u & 0xFFFF0000u);
}
__device__ __forceinline__ unsigned pack2(float a, float b) {
  return (unsigned)f2bf(a) | ((unsigned)f2bf(b) << 16);
}

// async global->LDS DMA, 16 B per lane (1 KB per wave-instruction).
// LDS dest must be wave-uniform base + lane*16; global src may be per-lane.
__device__ __forceinline__ void gload_lds16(const void* g, void* l) {
  __builtin_amdgcn_global_load_lds(
      (const __attribute__((address_space(1))) unsigned int*)g,
      (__attribute__((address_space(3))) unsigned int*)l, 16, 0, 0);
}

#define XBF_BLOCKS    25000   // N_NODES*IN_DIM/4 float4s / 256 threads
#define STARTS_BLOCKS 391     // ceil((N_SEG+1)/256)
#define W1T_BLOCKS    128     // 32768 float4s / 256
#define BW2_BLOCKS    2       // 512 entries / 256
#define CNT_BLOCKS    4       // 782 counters / 256

// ---------------- kernel 1: fused prep (xbf | seg_starts | w1t | bw2 | cnt=0) --------
__global__ void k_prep(const float* __restrict__ x, unsigned short* __restrict__ xb,
                       const int* __restrict__ ids, int* __restrict__ starts,
                       const float* __restrict__ W1, unsigned short* __restrict__ W1t,
                       const float* __restrict__ b1, const float* __restrict__ W2,
                       unsigned int* __restrict__ bw2, int* __restrict__ cnt) {
  const int b = blockIdx.x;
  const int tid = threadIdx.x;
  if (b < XBF_BLOCKS) {
    // x f32 -> xb bf16 (halves gather bytes)
    size_t idx = (size_t)b * 256 + tid;          // one float4 -> uint2 each
    float4 v = *(const float4*)(x + idx * 4);
    uint2 p;
    p.x = pack2(v.x, v.y);
    p.y = pack2(v.z, v.w);
    *(uint2*)(xb + idx * 4) = p;
  } else if (b < XBF_BLOCKS + STARTS_BLOCKS) {
    // starts[s] = first i with ids[i] >= s (ids sorted); starts[N_SEG] = N_INC
    int s = (b - XBF_BLOCKS) * 256 + tid;
    if (s > N_SEG) return;
    int lo = 0, hi = N_INC;
    while (lo < hi) {
      int mid = (lo + hi) >> 1;
      if (ids[mid] < s) lo = mid + 1; else hi = mid;
    }
    starts[s] = lo;
  } else if (b < XBF_BLOCKS + STARTS_BLOCKS + W1T_BLOCKS) {
    // W1 f32[256][512] -> W1t bf16[512][256]
    int idx = (b - XBF_BLOCKS - STARTS_BLOCKS) * 256 + tid;   // 0..32767
    int k  = idx >> 7;                           // 0..255
    int c4 = idx & 127;                          // float4 index along HIDDEN
    float4 v = *(const float4*)(W1 + (size_t)k * HIDDEN + c4 * 4);
    W1t[(c4 * 4 + 0) * IN_DIM + k] = f2bf(v.x);
    W1t[(c4 * 4 + 1) * IN_DIM + k] = f2bf(v.y);
    W1t[(c4 * 4 + 2) * IN_DIM + k] = f2bf(v.z);
    W1t[(c4 * 4 + 3) * IN_DIM + k] = f2bf(v.w);
  } else if (b < XBF_BLOCKS + STARTS_BLOCKS + W1T_BLOCKS + BW2_BLOCKS) {
    // pack (b1[c], W2[c]) -> bw2[c] as bf16 pair
    int c = (b - XBF_BLOCKS - STARTS_BLOCKS - W1T_BLOCKS) * 256 + tid;  // 0..511
    if (c < HIDDEN) bw2[c] = pack2(b1[c], W2[c]);
  } else {
    // zero the chunk-progress counters (MUST happen every launch: ws not re-poisoned)
    int i = (b - XBF_BLOCKS - STARTS_BLOCKS - W1T_BLOCKS - BW2_BLOCKS) * 256 + tid;
    if (i < NCHUNK) cnt[i] = 0;
  }
}

// ---------------- kernel 2: FUSED producer/consumer ----------------
// Group g (33 blocks): r=0..31 produce chunk g's 128 segments (4 segs/block, split-row
// gather as before) then signal cnt[g] (release). r=32 consumes: spin-waits cnt[g]==128
// (acquire), then v5-style DMA-staged MFMA MLP for rows [g*128, g*128+128), rf=2.
// Dispatch order puts producers before their consumer; liveness is capacity-guaranteed
// (<=782 spinners << resident slots). launch_bounds(256,4) caps VGPR at 128 to protect
// producer occupancy. C/D layout (m89-verified): col = lane&15, row = (lane>>4)*4 + e.
#define ACC8(v)                                                        \
  acc0 += bflo((v).x); acc1 += bfhi((v).x);                            \
  acc2 += bflo((v).y); acc3 += bfhi((v).y);                            \
  acc4 += bflo((v).z); acc5 += bfhi((v).z);                            \
  acc6 += bflo((v).w); acc7 += bfhi((v).w);

__global__ __launch_bounds__(256, 4) void k_fused(
    const unsigned short* __restrict__ xb, const int* __restrict__ nodes,
    const int* __restrict__ starts, const unsigned short* __restrict__ W1t,
    const unsigned int* __restrict__ bw2, const float* __restrict__ b2,
    unsigned short* __restrict__ Zb, int* __restrict__ cnt,
    float* __restrict__ out) {
  __shared__ __align__(16) unsigned short Bf[8][4][64][8];   // 32 KB (consumer role)
  const int g    = blockIdx.x / GRP;
  const int r    = blockIdx.x % GRP;
  const int tid  = threadIdx.x;
  const int wave = tid >> 6;
  const int lane = tid & 63;

  if (r < 32) {
    // ======== producer: segsum for segment s ========
    const int s = (g * 32 + r) * 4 + wave;
    if (s < N_SEG) {
      const int beg = starts[s];
      const int end = starts[s + 1];
      const int half = lane >> 5;
      const int sl   = lane & 31;
      const unsigned short* base = xb + sl * 8;
      float acc0 = 0.f, acc1 = 0.f, acc2 = 0.f, acc3 = 0.f;
      float acc4 = 0.f, acc5 = 0.f, acc6 = 0.f, acc7 = 0.f;
      int j = beg + half;
      for (; j + 6 < end; j += 8) {
        int n0 = nodes[j], n1 = nodes[j + 2], n2 = nodes[j + 4], n3 = nodes[j + 6];
        uint4 v0 = *(const uint4*)(base + (size_t)n0 * IN_DIM);
        uint4 v1 = *(const uint4*)(base + (size_t)n1 * IN_DIM);
        uint4 v2 = *(const uint4*)(base + (size_t)n2 * IN_DIM);
        uint4 v3 = *(const uint4*)(base + (size_t)n3 * IN_DIM);
        ACC8(v0); ACC8(v1); ACC8(v2); ACC8(v3);
      }
      for (; j < end; j += 2) {
        int n0 = nodes[j];
        uint4 v0 = *(const uint4*)(base + (size_t)n0 * IN_DIM);
        ACC8(v0);
      }
      acc0 += __shfl_xor(acc0, 32, 64);
      acc1 += __shfl_xor(acc1, 32, 64);
      acc2 += __shfl_xor(acc2, 32, 64);
      acc3 += __shfl_xor(acc3, 32, 64);
      acc4 += __shfl_xor(acc4, 32, 64);
      acc5 += __shfl_xor(acc5, 32, 64);
      acc6 += __shfl_xor(acc6, 32, 64);
      acc7 += __shfl_xor(acc7, 32, 64);
      if (half == 0) {
        uint4 p;
        p.x = pack2(acc0, acc1);
        p.y = pack2(acc2, acc3);
        p.z = pack2(acc4, acc5);
        p.w = pack2(acc6, acc7);
        *(uint4*)(Zb + (size_t)s * IN_DIM + sl * 8) = p;
      }
    }
    // signal (release): one per wave, even for padded s >= N_SEG
    if (lane == 0) {
      __threadfence();
      atomicAdd(&cnt[g], 1);
    }
    return;
  }

  // ======== consumer: MLP for chunk g (rows g*128 .. +127) ========
  // per-wave gate: spin until all 128 segment-signals of this chunk (acquire)
  if (lane == 0) {
    while (atomicAdd(&cnt[g], 0) < 128) __builtin_amdgcn_s_sleep(32);
    __threadfence();
  }
  // wave reconverges here; every wave independently gated

  const int m0 = g * 128 + wave * 32;
  const unsigned short* wsrc = W1t + (size_t)(wave * 16 + (lane & 15)) * IN_DIM
                                   + (lane >> 4) * 8;

  // A fragments: a[rf][kc], lane l holds Z[m0+rf*16+(l&15)][kc*32+(l>>4)*8 ..+8]
  uint4 a[2][8];
  const int arow = m0 + (lane & 15);
  const int ak   = (lane >> 4) * 8;
  #pragma unroll
  for (int kc = 0; kc < 8; ++kc) {
    #pragma unroll
    for (int rf = 0; rf < 2; ++rf) {
      int row = arow + rf * 16;
      if (row < N_SEG)
        a[rf][kc] = *(const uint4*)(Zb + (size_t)row * IN_DIM + kc * 32 + ak);
      else
        a[rf][kc] = make_uint4(0u, 0u, 0u, 0u);
    }
  }

  // b2 seeded once per 16-lane reduction group
  const float b2v = ((lane & 15) == 0) ? b2[0] : 0.f;
  float logit[2][4];
  #pragma unroll
  for (int rf = 0; rf < 2; ++rf)
    #pragma unroll
    for (int e = 0; e < 4; ++e) logit[rf][e] = b2v;

  for (int nt = 0; nt < 8; ++nt) {
    const int c0 = nt * 64;
    // stage B via async DMA: per it, this wave fills Bf[it][wave][*][*] (1 KB)
    #pragma unroll
    for (int it = 0; it < 8; ++it)
      gload_lds16(wsrc + (size_t)c0 * IN_DIM + it * 32, &Bf[it][wave][lane][0]);
    __syncthreads();   // drains vmcnt once

    f32x4 acc[2][4];
    #pragma unroll
    for (int rf = 0; rf < 2; ++rf)
      #pragma unroll
      for (int cf = 0; cf < 4; ++cf) acc[rf][cf] = (f32x4){0.f, 0.f, 0.f, 0.f};

    #pragma unroll
    for (int kc = 0; kc < 8; ++kc) {
      #pragma unroll
      for (int cf = 0; cf < 4; ++cf) {
        bf16x8 bv = *(const bf16x8*)&Bf[kc][cf][lane][0];
        #pragma unroll
        for (int rf = 0; rf < 2; ++rf) {
          bf16x8 av = __builtin_bit_cast(bf16x8, a[rf][kc]);
          acc[rf][cf] = __builtin_amdgcn_mfma_f32_16x16x32_bf16(av, bv, acc[rf][cf], 0, 0, 0);
        }
      }
    }

    // epilogue: bias + relu + dot with W2 (bw2 is L2-hit; not hoisted to save VGPR)
    #pragma unroll
    for (int cf = 0; cf < 4; ++cf) {
      int cc = c0 + cf * 16 + (lane & 15);
      unsigned int bw = bw2[cc];
      float bb = bflo(bw);
      float w2 = bfhi(bw);
      #pragma unroll
      for (int rf = 0; rf < 2; ++rf)
        #pragma unroll
        for (int e = 0; e < 4; ++e) {
          float h = acc[rf][cf][e] + bb;
          h = h > 0.f ? h : 0.f;
          logit[rf][e] = fmaf(h, w2, logit[rf][e]);
        }
    }
    __syncthreads();   // WAR: all waves done reading Bf before next stage
  }

  // reduce over the 16 lanes of each column group (lane&15)
  #pragma unroll
  for (int rf = 0; rf < 2; ++rf)
    #pragma unroll
    for (int e = 0; e < 4; ++e) {
      float v = logit[rf][e];
      v += __shfl_xor(v, 1, 64);
      v += __shfl_xor(v, 2, 64);
      v += __shfl_xor(v, 4, 64);
      v += __shfl_xor(v, 8, 64);
      logit[rf][e] = v;
    }
  if ((lane & 15) == 0) {
    #pragma unroll
    for (int rf = 0; rf < 2; ++rf)
      #pragma unroll
      for (int e = 0; e < 4; ++e) {
        int row = m0 + rf * 16 + (lane >> 4) * 4 + e;
        if (row < N_SEG)
          out[row] = 1.f / (1.f + expf(-logit[rf][e]));
      }
  }
}

extern "C" void kernel_launch(void* const* d_in, const int* in_sizes, int n_in,
                              void* d_out, int out_size, void* d_ws, size_t ws_size,
                              hipStream_t stream) {
  const float* x   = (const float*)d_in[0];
  const int* nodes = (const int*)d_in[1];
  const int* ids   = (const int*)d_in[2];
  const float* W1  = (const float*)d_in[4];
  const float* b1  = (const float*)d_in[5];
  const float* W2  = (const float*)d_in[6];
  const float* b2  = (const float*)d_in[7];
  float* out       = (float*)d_out;

  char* ws = (char*)d_ws;
  int* starts = (int*)ws;                                        // (N_SEG+1)*4 B
  size_t off = (((size_t)(N_SEG + 1) * sizeof(int)) + 1023) & ~(size_t)1023;
  unsigned short* Zb = (unsigned short*)(ws + off);              // 51.2 MB
  off += (size_t)N_NODES * IN_DIM * sizeof(unsigned short);
  off = (off + 1023) & ~(size_t)1023;
  unsigned short* W1t = (unsigned short*)(ws + off);             // 256 KB
  off += (size_t)HIDDEN * IN_DIM * sizeof(unsigned short);
  off = (off + 1023) & ~(size_t)1023;
  unsigned int* bw2 = (unsigned int*)(ws + off);                 // 2 KB
  off += (size_t)HIDDEN * sizeof(unsigned int);
  off = (off + 1023) & ~(size_t)1023;
  int* cnt = (int*)(ws + off);                                   // 3.1 KB
  off += (size_t)NCHUNK * sizeof(int);
  off = (off + 1023) & ~(size_t)1023;
  unsigned short* xb = (unsigned short*)(ws + off);              // 51.2 MB

  k_prep<<<XBF_BLOCKS + STARTS_BLOCKS + W1T_BLOCKS + BW2_BLOCKS + CNT_BLOCKS,
           256, 0, stream>>>(x, xb, ids, starts, W1, W1t, b1, W2, bw2, cnt);
  k_fused<<<NCHUNK * GRP, 256, 0, stream>>>(xb, nodes, starts, W1t, bw2, b2,
                                            Zb, cnt, out);
}

// Round 19
// 179.483 us; speedup vs baseline: 17.4446x; 17.4446x over previous
//
#include <hip/hip_runtime.h>
#include <hip/hip_bf16.h>
#include <math.h>

#define N_NODES   100000
#define IN_DIM    256
#define HIDDEN    512
#define N_INC     1000000
#define N_SEG     100000
#define NCHUNK    782          // ceil(N_SEG / 128)

typedef __attribute__((ext_vector_type(8))) short bf16x8;
typedef __attribute__((ext_vector_type(4))) float f32x4;

__device__ __forceinline__ unsigned short f2bf(float f) {
  unsigned int u = __builtin_bit_cast(unsigned int, f);
  u += 0x7FFFu + ((u >> 16) & 1u);   // RNE
  return (unsigned short)(u >> 16);
}
__device__ __forceinline__ float bflo(unsigned int u) {   // low bf16 -> f32
  return __builtin_bit_cast(float, u << 16);
}
__device__ __forceinline__ float bfhi(unsigned int u) {   // high bf16 -> f32
  return __builtin_bit_cast(float, u & 0xFFFF0000u);
}
__device__ __forceinline__ unsigned pack2(float a, float b) {
  return (unsigned)f2bf(a) | ((unsigned)f2bf(b) << 16);
}

// async global->LDS DMA, 16 B per lane (1 KB per wave-instruction).
// LDS dest must be wave-uniform base + lane*16; global src may be per-lane.
__device__ __forceinline__ void gload_lds16(const void* g, void* l) {
  __builtin_amdgcn_global_load_lds(
      (const __attribute__((address_space(1))) unsigned int*)g,
      (__attribute__((address_space(3))) unsigned int*)l, 16, 0, 0);
}

#define XBF_BLOCKS    25000   // N_NODES*IN_DIM/4 float4s / 256 threads
#define STARTS_BLOCKS 391     // ceil((N_SEG+1)/256)
#define W1T_BLOCKS    128     // 32768 float4s / 256
#define BW2_BLOCKS    2       // 512 entries / 256

// ---------------- kernel 1: fused prep (xbf | seg_starts | w1t | bw2) ----------
__global__ void k_prep(const float* __restrict__ x, unsigned short* __restrict__ xb,
                       const int* __restrict__ ids, int* __restrict__ starts,
                       const float* __restrict__ W1, unsigned short* __restrict__ W1t,
                       const float* __restrict__ b1, const float* __restrict__ W2,
                       unsigned int* __restrict__ bw2) {
  const int b = blockIdx.x;
  const int tid = threadIdx.x;
  if (b < XBF_BLOCKS) {
    // x f32 -> xb bf16 (halves gather bytes)
    size_t idx = (size_t)b * 256 + tid;          // one float4 -> uint2 each
    float4 v = *(const float4*)(x + idx * 4);
    uint2 p;
    p.x = pack2(v.x, v.y);
    p.y = pack2(v.z, v.w);
    *(uint2*)(xb + idx * 4) = p;
  } else if (b < XBF_BLOCKS + STARTS_BLOCKS) {
    // starts[s] = first i with ids[i] >= s (ids sorted); starts[N_SEG] = N_INC
    int s = (b - XBF_BLOCKS) * 256 + tid;
    if (s > N_SEG) return;
    int lo = 0, hi = N_INC;
    while (lo < hi) {
      int mid = (lo + hi) >> 1;
      if (ids[mid] < s) lo = mid + 1; else hi = mid;
    }
    starts[s] = lo;
  } else if (b < XBF_BLOCKS + STARTS_BLOCKS + W1T_BLOCKS) {
    // W1 f32[256][512] -> W1t bf16[512][256]
    int idx = (b - XBF_BLOCKS - STARTS_BLOCKS) * 256 + tid;   // 0..32767
    int k  = idx >> 7;                           // 0..255
    int c4 = idx & 127;                          // float4 index along HIDDEN
    float4 v = *(const float4*)(W1 + (size_t)k * HIDDEN + c4 * 4);
    W1t[(c4 * 4 + 0) * IN_DIM + k] = f2bf(v.x);
    W1t[(c4 * 4 + 1) * IN_DIM + k] = f2bf(v.y);
    W1t[(c4 * 4 + 2) * IN_DIM + k] = f2bf(v.z);
    W1t[(c4 * 4 + 3) * IN_DIM + k] = f2bf(v.w);
  } else {
    // pack (b1[c], W2[c]) -> bw2[c] as bf16 pair
    int c = (b - XBF_BLOCKS - STARTS_BLOCKS - W1T_BLOCKS) * 256 + tid;  // 0..511
    if (c < HIDDEN) bw2[c] = pack2(b1[c], W2[c]);
  }
}

// ---------------- kernel 2: FUSED block-local gather+segsum -> MLP ----------------
// Block g owns segments [g*128, g*128+128). NO cross-block dependency (round-18's
// spin-convoy lesson): wave w gathers its own 32 segments to Zb (global, lands in
// own-CU L1/L2), vmcnt-drain + block barrier, then wave w's MLP tile is EXACTLY the
// rows it wrote (same-wave RAW). LDS holds only B (32 KB) -> 4 blocks/CU; all 782
// blocks resident from t=0, gather finish times stagger so MFMA overlaps the fabric.
// launch_bounds(256,4) caps VGPR at 128 (rf=2: a[2][8]=64; bw2 NOT hoisted).
// C/D layout (m89-verified): col = lane&15, row = (lane>>4)*4 + e.
#define ACC8(v)                                                        \
  acc0 += bflo((v).x); acc1 += bfhi((v).x);                            \
  acc2 += bflo((v).y); acc3 += bfhi((v).y);                            \
  acc4 += bflo((v).z); acc5 += bfhi((v).z);                            \
  acc6 += bflo((v).w); acc7 += bfhi((v).w);

__global__ __launch_bounds__(256, 4) void k_fused2(
    const unsigned short* __restrict__ xb, const int* __restrict__ nodes,
    const int* __restrict__ starts, const unsigned short* __restrict__ W1t,
    const unsigned int* __restrict__ bw2, const float* __restrict__ b2,
    unsigned short* __restrict__ Zb, float* __restrict__ out) {
  __shared__ __align__(16) unsigned short Bf[8][4][64][8];   // [kc][cf][lane][e] 32 KB
  const int g    = blockIdx.x;
  const int tid  = threadIdx.x;
  const int wave = tid >> 6;
  const int lane = tid & 63;

  // ======== phase 1: gather + segsum for this wave's 32 segments ========
  {
    const int half = lane >> 5;
    const int sl   = lane & 31;
    const unsigned short* base = xb + sl * 8;
    for (int t = 0; t < 32; ++t) {
      const int s = g * 128 + wave * 32 + t;
      if (s >= N_SEG) break;
      const int beg = starts[s];
      const int end = starts[s + 1];
      float acc0 = 0.f, acc1 = 0.f, acc2 = 0.f, acc3 = 0.f;
      float acc4 = 0.f, acc5 = 0.f, acc6 = 0.f, acc7 = 0.f;
      int j = beg + half;
      for (; j + 6 < end; j += 8) {             // 4 rows per half per iter
        int n0 = nodes[j], n1 = nodes[j + 2], n2 = nodes[j + 4], n3 = nodes[j + 6];
        uint4 v0 = *(const uint4*)(base + (size_t)n0 * IN_DIM);
        uint4 v1 = *(const uint4*)(base + (size_t)n1 * IN_DIM);
        uint4 v2 = *(const uint4*)(base + (size_t)n2 * IN_DIM);
        uint4 v3 = *(const uint4*)(base + (size_t)n3 * IN_DIM);
        ACC8(v0); ACC8(v1); ACC8(v2); ACC8(v3);
      }
      for (; j < end; j += 2) {
        int n0 = nodes[j];
        uint4 v0 = *(const uint4*)(base + (size_t)n0 * IN_DIM);
        ACC8(v0);
      }
      acc0 += __shfl_xor(acc0, 32, 64);
      acc1 += __shfl_xor(acc1, 32, 64);
      acc2 += __shfl_xor(acc2, 32, 64);
      acc3 += __shfl_xor(acc3, 32, 64);
      acc4 += __shfl_xor(acc4, 32, 64);
      acc5 += __shfl_xor(acc5, 32, 64);
      acc6 += __shfl_xor(acc6, 32, 64);
      acc7 += __shfl_xor(acc7, 32, 64);
      if (half == 0) {
        uint4 p;
        p.x = pack2(acc0, acc1);
        p.y = pack2(acc2, acc3);
        p.z = pack2(acc4, acc5);
        p.w = pack2(acc6, acc7);
        *(uint4*)(Zb + (size_t)s * IN_DIM + sl * 8) = p;
      }
    }
  }
  asm volatile("s_waitcnt vmcnt(0)" ::: "memory");  // own stores landed (RAW safety)
  __syncthreads();

  // ======== phase 2: MLP for rows [g*128, g*128+128), wave tile = own 32 rows ========
  const int m0 = g * 128 + wave * 32;
  const unsigned short* wsrc = W1t + (size_t)(wave * 16 + (lane & 15)) * IN_DIM
                                   + (lane >> 4) * 8;

  // A fragments: a[rf][kc], lane l holds Z[m0+rf*16+(l&15)][kc*32+(l>>4)*8 ..+8]
  uint4 a[2][8];
  const int arow = m0 + (lane & 15);
  const int ak   = (lane >> 4) * 8;
  #pragma unroll
  for (int kc = 0; kc < 8; ++kc) {
    #pragma unroll
    for (int rf = 0; rf < 2; ++rf) {
      int row = arow + rf * 16;
      if (row < N_SEG)
        a[rf][kc] = *(const uint4*)(Zb + (size_t)row * IN_DIM + kc * 32 + ak);
      else
        a[rf][kc] = make_uint4(0u, 0u, 0u, 0u);
    }
  }

  // b2 seeded once per 16-lane reduction group (summed exactly once by shfl-reduce)
  const float b2v = ((lane & 15) == 0) ? b2[0] : 0.f;
  float logit[2][4];
  #pragma unroll
  for (int rf = 0; rf < 2; ++rf)
    #pragma unroll
    for (int e = 0; e < 4; ++e) logit[rf][e] = b2v;

  for (int nt = 0; nt < 8; ++nt) {
    const int c0 = nt * 64;
    // stage B via async DMA: per it, this wave fills Bf[it][wave][*][*] (1 KB)
    #pragma unroll
    for (int it = 0; it < 8; ++it)
      gload_lds16(wsrc + (size_t)c0 * IN_DIM + it * 32, &Bf[it][wave][lane][0]);
    __syncthreads();   // drains vmcnt once

    f32x4 acc[2][4];
    #pragma unroll
    for (int rf = 0; rf < 2; ++rf)
      #pragma unroll
      for (int cf = 0; cf < 4; ++cf) acc[rf][cf] = (f32x4){0.f, 0.f, 0.f, 0.f};

    #pragma unroll
    for (int kc = 0; kc < 8; ++kc) {
      #pragma unroll
      for (int cf = 0; cf < 4; ++cf) {
        bf16x8 bv = *(const bf16x8*)&Bf[kc][cf][lane][0];
        #pragma unroll
        for (int rf = 0; rf < 2; ++rf) {
          bf16x8 av = __builtin_bit_cast(bf16x8, a[rf][kc]);
          acc[rf][cf] = __builtin_amdgcn_mfma_f32_16x16x32_bf16(av, bv, acc[rf][cf], 0, 0, 0);
        }
      }
    }

    // epilogue: bias + relu + dot with W2 (bw2 from L2; not hoisted to keep VGPR<=128)
    #pragma unroll
    for (int cf = 0; cf < 4; ++cf) {
      int cc = c0 + cf * 16 + (lane & 15);
      unsigned int bw = bw2[cc];
      float bb = bflo(bw);
      float w2 = bfhi(bw);
      #pragma unroll
      for (int rf = 0; rf < 2; ++rf)
        #pragma unroll
        for (int e = 0; e < 4; ++e) {
          float h = acc[rf][cf][e] + bb;
          h = h > 0.f ? h : 0.f;
          logit[rf][e] = fmaf(h, w2, logit[rf][e]);
        }
    }
    __syncthreads();   // WAR: all waves done reading Bf before next stage
  }

  // reduce over the 16 lanes of each column group (lane&15)
  #pragma unroll
  for (int rf = 0; rf < 2; ++rf)
    #pragma unroll
    for (int e = 0; e < 4; ++e) {
      float v = logit[rf][e];
      v += __shfl_xor(v, 1, 64);
      v += __shfl_xor(v, 2, 64);
      v += __shfl_xor(v, 4, 64);
      v += __shfl_xor(v, 8, 64);
      logit[rf][e] = v;
    }
  if ((lane & 15) == 0) {
    #pragma unroll
    for (int rf = 0; rf < 2; ++rf)
      #pragma unroll
      for (int e = 0; e < 4; ++e) {
        int row = m0 + rf * 16 + (lane >> 4) * 4 + e;
        if (row < N_SEG)
          out[row] = 1.f / (1.f + expf(-logit[rf][e]));
      }
  }
}

extern "C" void kernel_launch(void* const* d_in, const int* in_sizes, int n_in,
                              void* d_out, int out_size, void* d_ws, size_t ws_size,
                              hipStream_t stream) {
  const float* x   = (const float*)d_in[0];
  const int* nodes = (const int*)d_in[1];
  const int* ids   = (const int*)d_in[2];
  const float* W1  = (const float*)d_in[4];
  const float* b1  = (const float*)d_in[5];
  const float* W2  = (const float*)d_in[6];
  const float* b2  = (const float*)d_in[7];
  float* out       = (float*)d_out;

  char* ws = (char*)d_ws;
  int* starts = (int*)ws;                                        // (N_SEG+1)*4 B
  size_t off = (((size_t)(N_SEG + 1) * sizeof(int)) + 1023) & ~(size_t)1023;
  unsigned short* Zb = (unsigned short*)(ws + off);              // 51.2 MB
  off += (size_t)N_NODES * IN_DIM * sizeof(unsigned short);
  off = (off + 1023) & ~(size_t)1023;
  unsigned short* W1t = (unsigned short*)(ws + off);             // 256 KB
  off += (size_t)HIDDEN * IN_DIM * sizeof(unsigned short);
  off = (off + 1023) & ~(size_t)1023;
  unsigned int* bw2 = (unsigned int*)(ws + off);                 // 2 KB
  off += (size_t)HIDDEN * sizeof(unsigned int);
  off = (off + 1023) & ~(size_t)1023;
  unsigned short* xb = (unsigned short*)(ws + off);              // 51.2 MB

  k_prep<<<XBF_BLOCKS + STARTS_BLOCKS + W1T_BLOCKS + BW2_BLOCKS, 256, 0, stream>>>(
      x, xb, ids, starts, W1, W1t, b1, W2, bw2);
  k_fused2<<<NCHUNK, 256, 0, stream>>>(xb, nodes, starts, W1t, bw2, b2, Zb, out);
}

// Round 20
// 149.494 us; speedup vs baseline: 20.9440x; 1.2006x over previous
//
#include <hip/hip_runtime.h>
#include <hip/hip_bf16.h>
#include <math.h>

#define N_NODES   100000
#define IN_DIM    256
#define HIDDEN    512
#define N_INC     1000000
#define N_SEG     100000

typedef __attribute__((ext_vector_type(8))) short bf16x8;
typedef __attribute__((ext_vector_type(4))) float f32x4;

__device__ __forceinline__ unsigned short f2bf(float f) {
  unsigned int u = __builtin_bit_cast(unsigned int, f);
  u += 0x7FFFu + ((u >> 16) & 1u);   // RNE
  return (unsigned short)(u >> 16);
}
__device__ __forceinline__ float bflo(unsigned int u) {   // low bf16 -> f32
  return __builtin_bit_cast(float, u << 16);
}
__device__ __forceinline__ float bfhi(unsigned int u) {   // high bf16 -> f32
  return __builtin_bit_cast(float, u & 0xFFFF0000u);
}
__device__ __forceinline__ unsigned pack2(float a, float b) {
  return (unsigned)f2bf(a) | ((unsigned)f2bf(b) << 16);
}

// async global->LDS DMA, 16 B per lane (1 KB per wave-instruction).
// LDS dest must be wave-uniform base + lane*16; global src may be per-lane.
__device__ __forceinline__ void gload_lds16(const void* g, void* l) {
  __builtin_amdgcn_global_load_lds(
      (const __attribute__((address_space(1))) unsigned int*)g,
      (__attribute__((address_space(3))) unsigned int*)l, 16, 0, 0);
}

#define XBF_BLOCKS    25000   // N_NODES*IN_DIM/4 float4s / 256 threads
#define STARTS_BLOCKS 391     // ceil((N_SEG+1)/256)
#define W1T_BLOCKS    128     // 32768 float4s / 256
#define BW2_BLOCKS    2       // 512 entries / 256

// ---------------- kernel 1: fused prep (xbf | seg_starts | w1t | bw2) ----------
__global__ void k_prep(const float* __restrict__ x, unsigned short* __restrict__ xb,
                       const int* __restrict__ ids, int* __restrict__ starts,
                       const float* __restrict__ W1, unsigned short* __restrict__ W1t,
                       const float* __restrict__ b1, const float* __restrict__ W2,
                       unsigned int* __restrict__ bw2) {
  const int b = blockIdx.x;
  const int tid = threadIdx.x;
  if (b < XBF_BLOCKS) {
    // x f32 -> xb bf16 (halves gather bytes)
    size_t idx = (size_t)b * 256 + tid;          // one float4 -> uint2 each
    float4 v = *(const float4*)(x + idx * 4);
    uint2 p;
    p.x = pack2(v.x, v.y);
    p.y = pack2(v.z, v.w);
    *(uint2*)(xb + idx * 4) = p;
  } else if (b < XBF_BLOCKS + STARTS_BLOCKS) {
    // starts[s] = first i with ids[i] >= s (ids sorted); starts[N_SEG] = N_INC
    int s = (b - XBF_BLOCKS) * 256 + tid;
    if (s > N_SEG) return;
    int lo = 0, hi = N_INC;
    while (lo < hi) {
      int mid = (lo + hi) >> 1;
      if (ids[mid] < s) lo = mid + 1; else hi = mid;
    }
    starts[s] = lo;
  } else if (b < XBF_BLOCKS + STARTS_BLOCKS + W1T_BLOCKS) {
    // W1 f32[256][512] -> W1t bf16[512][256]
    int idx = (b - XBF_BLOCKS - STARTS_BLOCKS) * 256 + tid;   // 0..32767
    int k  = idx >> 7;                           // 0..255
    int c4 = idx & 127;                          // float4 index along HIDDEN
    float4 v = *(const float4*)(W1 + (size_t)k * HIDDEN + c4 * 4);
    W1t[(c4 * 4 + 0) * IN_DIM + k] = f2bf(v.x);
    W1t[(c4 * 4 + 1) * IN_DIM + k] = f2bf(v.y);
    W1t[(c4 * 4 + 2) * IN_DIM + k] = f2bf(v.z);
    W1t[(c4 * 4 + 3) * IN_DIM + k] = f2bf(v.w);
  } else {
    // pack (b1[c], W2[c]) -> bw2[c] as bf16 pair (hoistable epilogue constants)
    int c = (b - XBF_BLOCKS - STARTS_BLOCKS - W1T_BLOCKS) * 256 + tid;  // 0..511
    if (c < HIDDEN) bw2[c] = pack2(b1[c], W2[c]);
  }
}

// ---------------- kernel 2: gather(bf16) + segment sum -> Zb bf16 ----------------
// Split-row: lanes 0-31 even incidences, lanes 32-63 odd; 16 B/lane (uint4) so one
// wave instruction covers TWO 512 B rows. Halves combined via shfl_xor(32).
// Pinned at the ~6.8 TB/s XCD-fabric/L3 roofline (rounds 3/4/7/8/19 converge;
// duration insensitive to source tier (HBM vs L3) and instruction-count halving;
// rate scales with resident gather waves -> needs full-occupancy dedicated kernel).
#define ACC8(v)                                                        \
  acc0 += bflo((v).x); acc1 += bfhi((v).x);                            \
  acc2 += bflo((v).y); acc3 += bfhi((v).y);                            \
  acc4 += bflo((v).z); acc5 += bfhi((v).z);                            \
  acc6 += bflo((v).w); acc7 += bfhi((v).w);

__global__ void k_segsum(const unsigned short* __restrict__ xb, const int* __restrict__ nodes,
                         const int* __restrict__ starts, unsigned short* __restrict__ Zb) {
  int wave = threadIdx.x >> 6;
  int lane = threadIdx.x & 63;
  int s = blockIdx.x * 4 + wave;
  if (s >= N_SEG) return;
  const int beg = starts[s];
  const int end = starts[s + 1];
  const int half = lane >> 5;
  const int sl   = lane & 31;
  const unsigned short* base = xb + sl * 8;    // this lane's 16B slice within any row
  float acc0 = 0.f, acc1 = 0.f, acc2 = 0.f, acc3 = 0.f;
  float acc4 = 0.f, acc5 = 0.f, acc6 = 0.f, acc7 = 0.f;
  int j = beg + half;
  for (; j + 6 < end; j += 8) {               // 4 rows per half per iter
    int n0 = nodes[j], n1 = nodes[j + 2], n2 = nodes[j + 4], n3 = nodes[j + 6];
    uint4 v0 = *(const uint4*)(base + (size_t)n0 * IN_DIM);
    uint4 v1 = *(const uint4*)(base + (size_t)n1 * IN_DIM);
    uint4 v2 = *(const uint4*)(base + (size_t)n2 * IN_DIM);
    uint4 v3 = *(const uint4*)(base + (size_t)n3 * IN_DIM);
    ACC8(v0); ACC8(v1); ACC8(v2); ACC8(v3);
  }
  for (; j < end; j += 2) {
    int n0 = nodes[j];
    uint4 v0 = *(const uint4*)(base + (size_t)n0 * IN_DIM);
    ACC8(v0);
  }
  acc0 += __shfl_xor(acc0, 32, 64);
  acc1 += __shfl_xor(acc1, 32, 64);
  acc2 += __shfl_xor(acc2, 32, 64);
  acc3 += __shfl_xor(acc3, 32, 64);
  acc4 += __shfl_xor(acc4, 32, 64);
  acc5 += __shfl_xor(acc5, 32, 64);
  acc6 += __shfl_xor(acc6, 32, 64);
  acc7 += __shfl_xor(acc7, 32, 64);
  if (half == 0) {
    uint4 p;
    p.x = pack2(acc0, acc1);
    p.y = pack2(acc2, acc3);
    p.z = pack2(acc4, acc5);
    p.w = pack2(acc6, acc7);
    *(uint4*)(Zb + (size_t)s * IN_DIM + sl * 8) = p;
  }
}

// ---------------- kernel 3: MFMA MLP v9 — 8-wave blocks, dbuf DMA, hoisted epilogue ----
// Block: 512 thr / 8 waves; block tile 256 rows; wave tile 32 rows (rf=2); grid 391.
// B double-buffered (2 x 32 KB); per phase each wave stages its kc=wave slice of the
// NEXT tile (4 DMAs, 16 B/lane), then counted `s_waitcnt vmcnt(4)` + raw barrier +
// sched_barrier(0). Epilogue constants hoisted to 32 regs (bw2) -> loop has no VMEM
// besides DMAs. C/D layout (m89-verified): col = lane&15, row = (lane>>4)*4 + e.
// Best measured k_mlp variant (~41 us) of ten structural alternatives.
__global__ __launch_bounds__(512, 3) void k_mlp(
    const unsigned short* __restrict__ Zb, const unsigned short* __restrict__ W1t,
    const unsigned int* __restrict__ bw2, const float* __restrict__ b2,
    float* __restrict__ out) {
  __shared__ __align__(16) unsigned short Bf[2][8][4][64][8];  // [buf][kc][cf][lane][e] 64 KB
  const int tid  = threadIdx.x;
  const int wave = tid >> 6;         // 0..7
  const int lane = tid & 63;
  const int m0   = blockIdx.x * 256 + wave * 32;

  // per-lane global source base for this wave's B slice: kc = wave, cf = j:
  // src = W1t[(c0 + j*16 + (lane&15)) * 256 + wave*32 + (lane>>4)*8]
  const unsigned short* wsrc = W1t + (size_t)(lane & 15) * IN_DIM
                                   + wave * 32 + (lane >> 4) * 8;

  // prologue: stage tile 0 into buffer 0 (4 DMAs/wave, fire-and-forget)
  #pragma unroll
  for (int j = 0; j < 4; ++j)
    gload_lds16(wsrc + (size_t)(j * 16) * IN_DIM, &Bf[0][wave][j][lane][0]);

  // hoist epilogue constants: bw2r[nt*4+cf] = packed (b1,W2) at col
  // c = nt*64 + cf*16 + (lane&15)   (32 uint regs)
  unsigned int bw2r[32];
  #pragma unroll
  for (int i = 0; i < 32; ++i)
    bw2r[i] = bw2[(i >> 2) * 64 + (i & 3) * 16 + (lane & 15)];

  // A fragments (overlap with tile-0 DMA latency): a[rf][kc],
  // lane l holds Z[m0+rf*16+(l&15)][kc*32+(l>>4)*8 ..+8]
  uint4 a[2][8];
  const int arow = m0 + (lane & 15);
  const int ak   = (lane >> 4) * 8;
  #pragma unroll
  for (int kc = 0; kc < 8; ++kc) {
    #pragma unroll
    for (int rf = 0; rf < 2; ++rf) {
      int row = arow + rf * 16;
      if (row < N_SEG)
        a[rf][kc] = *(const uint4*)(Zb + (size_t)row * IN_DIM + kc * 32 + ak);
      else
        a[rf][kc] = make_uint4(0u, 0u, 0u, 0u);
    }
  }

  // b2 seeded once per 16-lane reduction group (summed exactly once by shfl-reduce)
  const float b2v = ((lane & 15) == 0) ? b2[0] : 0.f;
  float logit[2][4];
  #pragma unroll
  for (int rf = 0; rf < 2; ++rf)
    #pragma unroll
    for (int e = 0; e < 4; ++e) logit[rf][e] = b2v;

  #pragma unroll
  for (int nt = 0; nt < 8; ++nt) {
    const int cur = nt & 1;
    // stage NEXT tile's slice (4 DMAs), then wait for CURRENT tile only
    if (nt < 7) {
      const size_t csrc = (size_t)((nt + 1) * 64) * IN_DIM;
      #pragma unroll
      for (int j = 0; j < 4; ++j)
        gload_lds16(wsrc + csrc + (size_t)(j * 16) * IN_DIM, &Bf[cur ^ 1][wave][j][lane][0]);
      asm volatile("s_waitcnt vmcnt(4)" ::: "memory");  // current landed, next in flight
    } else {
      asm volatile("s_waitcnt vmcnt(0)" ::: "memory");  // epilogue: drain last tile
    }
    __builtin_amdgcn_s_barrier();          // all waves' current-tile DMAs landed
    __builtin_amdgcn_sched_barrier(0);     // no motion across the wait (rule #18)

    f32x4 acc[2][4];
    #pragma unroll
    for (int rf = 0; rf < 2; ++rf)
      #pragma unroll
      for (int cf = 0; cf < 4; ++cf) acc[rf][cf] = (f32x4){0.f, 0.f, 0.f, 0.f};

    #pragma unroll
    for (int kc = 0; kc < 8; ++kc) {
      #pragma unroll
      for (int cf = 0; cf < 4; ++cf) {
        bf16x8 bv = *(const bf16x8*)&Bf[cur][kc][cf][lane][0];
        #pragma unroll
        for (int rf = 0; rf < 2; ++rf) {
          bf16x8 av = __builtin_bit_cast(bf16x8, a[rf][kc]);
          acc[rf][cf] = __builtin_amdgcn_mfma_f32_16x16x32_bf16(av, bv, acc[rf][cf], 0, 0, 0);
        }
      }
    }

    // epilogue for this 64-col tile: bias + relu + dot with W2 (pure VALU, no VMEM)
    #pragma unroll
    for (int cf = 0; cf < 4; ++cf) {
      unsigned int bw = bw2r[nt * 4 + cf];
      float bb = bflo(bw);
      float w2 = bfhi(bw);
      #pragma unroll
      for (int rf = 0; rf < 2; ++rf)
        #pragma unroll
        for (int e = 0; e < 4; ++e) {
          float h = acc[rf][cf][e] + bb;
          h = h > 0.f ? h : 0.f;
          logit[rf][e] = fmaf(h, w2, logit[rf][e]);
        }
    }
    __builtin_amdgcn_s_barrier();          // WAR: all waves done reading Bf[cur]
  }

  // reduce over the 16 lanes of each column group (lane&15)
  #pragma unroll
  for (int rf = 0; rf < 2; ++rf)
    #pragma unroll
    for (int e = 0; e < 4; ++e) {
      float v = logit[rf][e];
      v += __shfl_xor(v, 1, 64);
      v += __shfl_xor(v, 2, 64);
      v += __shfl_xor(v, 4, 64);
      v += __shfl_xor(v, 8, 64);
      logit[rf][e] = v;
    }
  if ((lane & 15) == 0) {
    #pragma unroll
    for (int rf = 0; rf < 2; ++rf)
      #pragma unroll
      for (int e = 0; e < 4; ++e) {
        int row = m0 + rf * 16 + (lane >> 4) * 4 + e;
        if (row < N_SEG)
          out[row] = 1.f / (1.f + expf(-logit[rf][e]));
      }
  }
}

extern "C" void kernel_launch(void* const* d_in, const int* in_sizes, int n_in,
                              void* d_out, int out_size, void* d_ws, size_t ws_size,
                              hipStream_t stream) {
  const float* x   = (const float*)d_in[0];
  const int* nodes = (const int*)d_in[1];
  const int* ids   = (const int*)d_in[2];
  const float* W1  = (const float*)d_in[4];
  const float* b1  = (const float*)d_in[5];
  const float* W2  = (const float*)d_in[6];
  const float* b2  = (const float*)d_in[7];
  float* out       = (float*)d_out;

  char* ws = (char*)d_ws;
  int* starts = (int*)ws;                                        // (N_SEG+1)*4 B
  size_t off = (((size_t)(N_SEG + 1) * sizeof(int)) + 1023) & ~(size_t)1023;
  unsigned short* Zb = (unsigned short*)(ws + off);              // 51.2 MB
  off += (size_t)N_NODES * IN_DIM * sizeof(unsigned short);
  off = (off + 1023) & ~(size_t)1023;
  unsigned short* W1t = (unsigned short*)(ws + off);             // 256 KB
  off += (size_t)HIDDEN * IN_DIM * sizeof(unsigned short);
  off = (off + 1023) & ~(size_t)1023;
  unsigned int* bw2 = (unsigned int*)(ws + off);                 // 2 KB
  off += (size_t)HIDDEN * sizeof(unsigned int);
  off = (off + 1023) & ~(size_t)1023;
  unsigned short* xb = (unsigned short*)(ws + off);              // 51.2 MB

  k_prep<<<XBF_BLOCKS + STARTS_BLOCKS + W1T_BLOCKS + BW2_BLOCKS, 256, 0, stream>>>(
      x, xb, ids, starts, W1, W1t, b1, W2, bw2);
  k_segsum<<<(N_SEG + 3) / 4, 256, 0, stream>>>(xb, nodes, starts, Zb);
  k_mlp<<<(N_SEG + 255) / 256, 512, 0, stream>>>(Zb, W1t, bw2, b2, out);
}